// Round 1
// baseline (9910.619 us; speedup 1.0000x reference)
//
#include <hip/hip_runtime.h>
#include <math.h>

#define NFREQ 512
#define NSEC 16
#define NITER 1000
#define LRATE 0.1f
#define EPSF 1e-8f

__device__ __forceinline__ float rcpf(float x) { return __builtin_amdgcn_rcpf(x); }

// One block of 256 threads (4 waves, 1 wave/SIMD on one CU).
// Each thread owns frequencies t and t+256.
__global__ __launch_bounds__(256, 1)
void sgd_filter_design_kernel(const float* __restrict__ target,
                              const float* __restrict__ sos_init,
                              float* __restrict__ out)
{
    const int t = threadIdx.x;
    __shared__ float sos[96];        // 16 sections x 6 coefs [b0 b1 b2 a0 a1 a2]
    __shared__ float wgrad[4][96];   // per-wave reduced gradients

    if (t < 96) sos[t] = sos_init[t];
    __syncthreads();

    // Per-thread frequency constants: w = pi*n/511, n in {t, t+256}
    const float PI = 3.14159265358979323846f;
    float c1[2], s1[2], c2[2], s2[2], tgt[2];
    #pragma unroll
    for (int k = 0; k < 2; ++k) {
        const int n = t + k * 256;
        const float w = PI * (float)n / 511.0f;
        const float cc = cosf(w), ss = sinf(w);
        c1[k] = cc; s1[k] = ss;
        c2[k] = 2.0f * cc * cc - 1.0f;   // cos 2w
        s2[k] = 2.0f * ss * cc;          // sin 2w
        tgt[k] = target[n];
    }

    const int wv = t >> 6;
    const int lane = t & 63;

    for (int it = 0; it < NITER; ++it) {
        float acc[96];   // per-thread gradient partials (summed over its 2 freqs)

        #pragma unroll
        for (int k = 0; k < 2; ++k) {
            const float C1 = c1[k], S1 = s1[k], C2 = c2[k], S2 = s2[k];
            float S[96];             // grad direction terms for this freq
            float hr = 1.0f, hi = 0.0f;

            #pragma unroll
            for (int s = 0; s < NSEC; ++s) {
                const float b0 = sos[6*s+0], b1 = sos[6*s+1], b2 = sos[6*s+2];
                const float a0 = sos[6*s+3], a1 = sos[6*s+4], a2 = sos[6*s+5];
                // num = b0 + b1 z^-1 + b2 z^-2 at z^-1 = e^{-jw}
                const float nr = b0 + b1 * C1 + b2 * C2;
                const float ni = -(b1 * S1 + b2 * S2);
                const float dr = a0 + a1 * C1 + a2 * C2;
                const float di = -(a1 * S1 + a2 * S2);
                const float mn = nr*nr + ni*ni;
                const float md = dr*dr + di*di;
                const float imn = rcpf(mn);
                const float imd = rcpf(md);
                // h *= num/den  (as num * conj(den) / |den|^2, section order 0..15)
                const float tr = (nr*dr + ni*di) * imd;
                const float ti = (ni*dr - nr*di) * imd;
                const float nhr = hr*tr - hi*ti;
                const float nhi = hr*ti + hi*tr;
                hr = nhr; hi = nhi;
                // gradient directions (to be scaled by K):
                //   d mag / d b_c  ~  Re(p_c conj(num))/|num|^2 = cos(cw)*nr*imn - sin(cw)*ni*imn
                //   d mag / d a_c  ~ -Re(p_c conj(den))/|den|^2
                const float Ur = nr * imn, Ui = -(ni * imn);
                const float Vr = -(dr * imd), Vi = di * imd;
                S[6*s+0] = Ur;
                S[6*s+1] = C1*Ur + S1*Ui;
                S[6*s+2] = C2*Ur + S2*Ui;
                S[6*s+3] = Vr;
                S[6*s+4] = C1*Vr + S1*Vi;
                S[6*s+5] = C2*Vr + S2*Vi;
            }

            const float m2 = hr*hr + hi*hi;
            const float ah = sqrtf(m2);
            const float A = ah + EPSF;
            const float mag = 6.0205999132796239f * __log2f(A);  // 20*log10(A)
            const float diff = mag - tgt[k];
            // K = (2/512)*diff * (20/ln10) * |h|/(|h|+eps)
            const float K = diff * (2.0f * 8.685889638065035f / 512.0f) * ah * rcpf(A);

            #pragma unroll
            for (int g = 0; g < 96; ++g) {
                if (k == 0) acc[g] = K * S[g];
                else        acc[g] += K * S[g];
            }
        }

        // wave-level butterfly all-reduce of 96 partials
        #pragma unroll
        for (int g = 0; g < 96; ++g) {
            float v = acc[g];
            v += __shfl_xor(v, 1);
            v += __shfl_xor(v, 2);
            v += __shfl_xor(v, 4);
            v += __shfl_xor(v, 8);
            v += __shfl_xor(v, 16);
            v += __shfl_xor(v, 32);
            acc[g] = v;
        }

        if (lane == 0) {
            #pragma unroll
            for (int g = 0; g < 96; ++g) wgrad[wv][g] = acc[g];
        }
        __syncthreads();

        if (t < 96) {
            const float gsum = wgrad[0][t] + wgrad[1][t] + wgrad[2][t] + wgrad[3][t];
            sos[t] -= LRATE * gsum;
        }
        __syncthreads();
    }

    if (t < 96) out[t] = sos[t];
}

extern "C" void kernel_launch(void* const* d_in, const int* in_sizes, int n_in,
                              void* d_out, int out_size, void* d_ws, size_t ws_size,
                              hipStream_t stream) {
    const float* target   = (const float*)d_in[0];   // (512,)
    const float* sos_init = (const float*)d_in[1];   // (1,16,6) = 96
    float* out = (float*)d_out;                      // 96 floats
    hipLaunchKernelGGL(sgd_filter_design_kernel, dim3(1), dim3(256), 0, stream,
                       target, sos_init, out);
}

// Round 2
// 3298.444 us; speedup vs baseline: 3.0046x; 3.0046x over previous
//
#include <hip/hip_runtime.h>
#include <math.h>

#define NITER 1000
#define LRATE 0.1f
#define EPSF 1e-8f

__device__ __forceinline__ float rcpf(float x) { return __builtin_amdgcn_rcpf(x); }

// Exchange with DPP partner (compile-time pattern). Involutions only:
// 0xB1 = quad_perm [1,0,3,2]  -> lane^1
// 0x4E = quad_perm [2,3,0,1]  -> lane^2
// 0x128 = row_ror:8 (within 16) -> lane^8
template<int CTRL>
__device__ __forceinline__ float dpp_xchg(float v) {
    int r = __builtin_amdgcn_update_dpp(0, __float_as_int(v), CTRL, 0xF, 0xF, true);
    return __int_as_float(r);
}

// One block, 256 threads (4 waves = 1 wave/SIMD). Thread owns freqs t, t+256.
__global__ __launch_bounds__(256, 1)
void sgd_filter_design_kernel(const float* __restrict__ target,
                              const float* __restrict__ sos_init,
                              float* __restrict__ out)
{
    const int t = threadIdx.x;
    const int wv = t >> 6;
    const int lane = t & 63;

    __shared__ __align__(16) float sos[96];
    __shared__ float wgrad[4][128];

    if (t < 96) sos[t] = sos_init[t];

    // per-thread frequency constants: w = pi*n/511
    const float PI = 3.14159265358979323846f;
    float c1[2], s1[2], c2[2], s2[2], tgt[2];
    #pragma unroll
    for (int k = 0; k < 2; ++k) {
        const int n = t + k * 256;
        const float w = PI * (float)n / 511.0f;
        const float cc = cosf(w), ss = sinf(w);
        c1[k] = cc; s1[k] = ss;
        c2[k] = 2.0f * cc * cc - 1.0f;
        s2[k] = 2.0f * ss * cc;
        tgt[k] = target[n];
    }

    // reduce-scatter destination base: depth weights {64,32,16,8,4,2} keyed by
    // lane bits {0,1,3,2,4,5} (mask order 1,2,8,4,16,32)
    const int base = ((lane & 1) << 6) | ((lane & 2) << 4) | ((lane & 8) << 1)
                   | ((lane & 4) << 1) | ((lane & 16) >> 2) | ((lane & 32) >> 4);

    __syncthreads();

    for (int it = 0; it < NITER; ++it) {
        // broadcast-load sos into registers (24x ds_read_b128, uniform addr)
        float rs[96];
        #pragma unroll
        for (int i = 0; i < 24; ++i) {
            float4 v = *reinterpret_cast<float4*>(&sos[i * 4]);
            rs[i*4+0] = v.x; rs[i*4+1] = v.y; rs[i*4+2] = v.z; rs[i*4+3] = v.w;
        }

        // ---- Pass A: forward -> K per frequency ----
        float Ks[2];
        #pragma unroll
        for (int k = 0; k < 2; ++k) {
            const float C1 = c1[k], S1 = s1[k], C2 = c2[k], S2 = s2[k];
            float hr = 1.0f, hi = 0.0f;
            #pragma unroll
            for (int s = 0; s < 16; ++s) {
                const float b0 = rs[6*s+0], b1 = rs[6*s+1], b2 = rs[6*s+2];
                const float a0 = rs[6*s+3], a1 = rs[6*s+4], a2 = rs[6*s+5];
                const float nr = fmaf(b2, C2, fmaf(b1, C1, b0));
                const float ni = -fmaf(b2, S2, b1 * S1);
                const float dr = fmaf(a2, C2, fmaf(a1, C1, a0));
                const float di = -fmaf(a2, S2, a1 * S1);
                const float md = fmaf(dr, dr, di * di);
                const float imd = rcpf(md);
                const float tr = fmaf(nr, dr, ni * di) * imd;
                const float ti = fmaf(ni, dr, -nr * di) * imd;
                const float nh = fmaf(hr, tr, -hi * ti);
                hi = fmaf(hr, ti, hi * tr);
                hr = nh;
            }
            const float m2 = fmaf(hr, hr, hi * hi);
            const float ah = sqrtf(m2);
            const float A = ah + EPSF;
            const float mag = 6.0205999132796239f * __log2f(A);   // 20*log10
            Ks[k] = (mag - tgt[k]) * (2.0f * 8.685889638065035f / 512.0f)
                    * ah * rcpf(A);
        }

        // ---- Pass B: recompute sections, accumulate gradient partials ----
        float acc[96];
        #pragma unroll
        for (int k = 0; k < 2; ++k) {
            const float C1 = c1[k], S1 = s1[k], C2 = c2[k], S2 = s2[k];
            const float Kk = Ks[k];
            #pragma unroll
            for (int s = 0; s < 16; ++s) {
                const float b0 = rs[6*s+0], b1 = rs[6*s+1], b2 = rs[6*s+2];
                const float a0 = rs[6*s+3], a1 = rs[6*s+4], a2 = rs[6*s+5];
                const float nr = fmaf(b2, C2, fmaf(b1, C1, b0));
                const float ni = -fmaf(b2, S2, b1 * S1);
                const float dr = fmaf(a2, C2, fmaf(a1, C1, a0));
                const float di = -fmaf(a2, S2, a1 * S1);
                const float mn = fmaf(nr, nr, ni * ni);
                const float md = fmaf(dr, dr, di * di);
                const float tU = Kk * rcpf(mn);
                const float tV = Kk * rcpf(md);
                const float KUr = tU * nr;
                const float KUi = -(tU * ni);
                const float KVr = -(tV * dr);
                const float KVi = tV * di;
                if (k == 0) {
                    acc[6*s+0] = KUr;
                    acc[6*s+1] = fmaf(C1, KUr, S1 * KUi);
                    acc[6*s+2] = fmaf(C2, KUr, S2 * KUi);
                    acc[6*s+3] = KVr;
                    acc[6*s+4] = fmaf(C1, KVr, S1 * KVi);
                    acc[6*s+5] = fmaf(C2, KVr, S2 * KVi);
                } else {
                    acc[6*s+0] += KUr;
                    acc[6*s+1] = fmaf(C1, KUr, fmaf(S1, KUi, acc[6*s+1]));
                    acc[6*s+2] = fmaf(C2, KUr, fmaf(S2, KUi, acc[6*s+2]));
                    acc[6*s+3] += KVr;
                    acc[6*s+4] = fmaf(C1, KVr, fmaf(S1, KVi, acc[6*s+4]));
                    acc[6*s+5] = fmaf(C2, KVr, fmaf(S2, KVi, acc[6*s+5]));
                }
            }
        }

        // ---- Wave reduce-scatter: 128 (96 + zero pad) -> 2 per lane ----
        float red[64];
        {   // depth 0: mask 1 (DPP), keep-weight 64
            const bool up = (lane & 1);
            #pragma unroll
            for (int i = 0; i < 64; ++i) {
                const float lo = acc[i];
                const float hh = (i + 64 < 96) ? acc[i + 64] : 0.0f;
                const float send = up ? lo : hh;
                const float recv = dpp_xchg<0xB1>(send);
                red[i] = (up ? hh : lo) + recv;
            }
        }
        {   // depth 1: mask 2 (DPP), weight 32
            const bool up = (lane & 2);
            #pragma unroll
            for (int i = 0; i < 32; ++i) {
                const float lo = red[i], hh = red[i + 32];
                const float send = up ? lo : hh;
                const float recv = dpp_xchg<0x4E>(send);
                red[i] = (up ? hh : lo) + recv;
            }
        }
        {   // depth 2: mask 8 (DPP row_ror:8), weight 16
            const bool up = (lane & 8);
            #pragma unroll
            for (int i = 0; i < 16; ++i) {
                const float lo = red[i], hh = red[i + 16];
                const float send = up ? lo : hh;
                const float recv = dpp_xchg<0x128>(send);
                red[i] = (up ? hh : lo) + recv;
            }
        }
        {   // depth 3: mask 4 (shfl), weight 8
            const bool up = (lane & 4);
            #pragma unroll
            for (int i = 0; i < 8; ++i) {
                const float lo = red[i], hh = red[i + 8];
                const float send = up ? lo : hh;
                const float recv = __shfl_xor(send, 4);
                red[i] = (up ? hh : lo) + recv;
            }
        }
        {   // depth 4: mask 16 (shfl), weight 4
            const bool up = (lane & 16);
            #pragma unroll
            for (int i = 0; i < 4; ++i) {
                const float lo = red[i], hh = red[i + 4];
                const float send = up ? lo : hh;
                const float recv = __shfl_xor(send, 16);
                red[i] = (up ? hh : lo) + recv;
            }
        }
        {   // depth 5: mask 32 (shfl), weight 2
            const bool up = (lane & 32);
            #pragma unroll
            for (int i = 0; i < 2; ++i) {
                const float lo = red[i], hh = red[i + 2];
                const float send = up ? lo : hh;
                const float recv = __shfl_xor(send, 32);
                red[i] = (up ? hh : lo) + recv;
            }
        }

        // lane owns g = base, base+1 (per-wave partial)
        wgrad[wv][base]     = red[0];
        wgrad[wv][base + 1] = red[1];
        __syncthreads();

        if (t < 96) {
            const float g = wgrad[0][t] + wgrad[1][t] + wgrad[2][t] + wgrad[3][t];
            sos[t] = fmaf(-LRATE, g, sos[t]);
        }
        __syncthreads();
    }

    if (t < 96) out[t] = sos[t];
}

extern "C" void kernel_launch(void* const* d_in, const int* in_sizes, int n_in,
                              void* d_out, int out_size, void* d_ws, size_t ws_size,
                              hipStream_t stream) {
    const float* target   = (const float*)d_in[0];   // (512,)
    const float* sos_init = (const float*)d_in[1];   // (1,16,6) = 96
    float* out = (float*)d_out;                      // 96 floats
    hipLaunchKernelGGL(sgd_filter_design_kernel, dim3(1), dim3(256), 0, stream,
                       target, sos_init, out);
}

// Round 3
// 2283.432 us; speedup vs baseline: 4.3402x; 1.4445x over previous
//
#include <hip/hip_runtime.h>
#include <math.h>

#define NITER 1000
#define LRATE 0.1f

typedef float v2f __attribute__((ext_vector_type(2)));
typedef unsigned int v2u __attribute__((ext_vector_type(2)));

__device__ __forceinline__ float rcpf(float x) { return __builtin_amdgcn_rcpf(x); }

template<int CTRL>
__device__ __forceinline__ float dpp_mov(float v) {
    return __int_as_float(__builtin_amdgcn_update_dpp(0, __float_as_int(v), CTRL, 0xF, 0xF, true));
}

__device__ __forceinline__ int lane_id() {
    return __builtin_amdgcn_mbcnt_hi(~0u, __builtin_amdgcn_mbcnt_lo(~0u, 0u));
}

// Swap 16-lane rows between two registers: x:{r0,y0,r2,y2}, y:{x1,r1,x3,r3}
__device__ __forceinline__ void swap16(float& x, float& y) {
#if __has_builtin(__builtin_amdgcn_permlane16_swap)
    v2u r = __builtin_amdgcn_permlane16_swap(__float_as_uint(x), __float_as_uint(y), false, false);
    x = __uint_as_float(r[0]);
    y = __uint_as_float(r[1]);
#else
    const bool up = lane_id() & 16;
    const float send = up ? x : y;
    const float recv = __shfl_xor(send, 16);
    x = up ? recv : x;
    y = up ? y : recv;
#endif
}

// Swap 32-lane halves between two registers
__device__ __forceinline__ void swap32(float& x, float& y) {
#if __has_builtin(__builtin_amdgcn_permlane32_swap)
    v2u r = __builtin_amdgcn_permlane32_swap(__float_as_uint(x), __float_as_uint(y), false, false);
    x = __uint_as_float(r[0]);
    y = __uint_as_float(r[1]);
#else
    const bool up = lane_id() & 32;
    const float send = up ? x : y;
    const float recv = __shfl_xor(send, 32);
    x = up ? recv : x;
    y = up ? y : recv;
#endif
}

// One block, 256 threads (4 waves = 1 wave/SIMD). Thread owns freqs t, t+256.
__global__ __launch_bounds__(256, 1)
void sgd_filter_design_kernel(const float* __restrict__ target,
                              const float* __restrict__ sos_init,
                              float* __restrict__ out)
{
    const int t = threadIdx.x;
    const int wv = t >> 6;
    const int lane = t & 63;

    __shared__ __align__(16) float sosT[96];   // transposed: sosT[c*16 + s]
    __shared__ float wgrad[4][128];

    if (t < 96) sosT[(t % 6) * 16 + (t / 6)] = sos_init[t];

    // per-freq constants as broadcast pairs (loop-invariant registers)
    const float PI = 3.14159265358979323846f;
    v2f c1p[2], s1p[2], c2p[2], s2p[2];
    float tgt[2];
    #pragma unroll
    for (int k = 0; k < 2; ++k) {
        const int n = t + k * 256;
        const float w = PI * (float)n / 511.0f;
        const float cc = cosf(w), ss = sinf(w);
        const float c2 = 2.0f * cc * cc - 1.0f;
        const float s2 = 2.0f * ss * cc;
        v2f vc1 = {cc, cc}, vs1 = {ss, ss}, vc2 = {c2, c2}, vs2 = {s2, s2};
        c1p[k] = vc1; s1p[k] = vs1; c2p[k] = vc2; s2p[k] = vs2;
        tgt[k] = target[n];
    }

    // butterfly ownership base; level order [16,32,1,2,8,4] -> weights [64..2]
    const int base = ((lane & 16) << 2) | (lane & 32) | ((lane & 1) << 4)
                   | ((lane & 2) << 2) | ((lane & 8) >> 1) | ((lane & 4) >> 1);
    const bool up1 = lane & 1, up2 = lane & 2, up8 = lane & 8, up4 = lane & 4;

    __syncthreads();

    for (int it = 0; it < NITER; ++it) {
        // broadcast-load transposed coefs as section-pair packed registers
        v2f cs[6][8];
        #pragma unroll
        for (int c = 0; c < 6; ++c) {
            #pragma unroll
            for (int jj = 0; jj < 4; ++jj) {
                const float4 v = *reinterpret_cast<const float4*>(&sosT[c * 16 + jj * 4]);
                v2f lo = {v.x, v.y}, hi = {v.z, v.w};
                cs[c][2 * jj]     = lo;
                cs[c][2 * jj + 1] = hi;
            }
        }

        v2f accv[6][8];   // accv[c][j] = grad for coef c, sections (2j, 2j+1)

        #pragma unroll
        for (int k = 0; k < 2; ++k) {
            const v2f C1 = c1p[k], S1 = s1p[k], C2 = c2p[k], S2 = s2p[k];
            v2f Ur[8], Ui[8], Vr[8], Vi[8];
            v2f qp = {1.0f, 1.0f};
            #pragma unroll
            for (int j = 0; j < 8; ++j) {
                const v2f b0 = cs[0][j], b1 = cs[1][j], b2 = cs[2][j];
                const v2f a0 = cs[3][j], a1 = cs[4][j], a2 = cs[5][j];
                const v2f nr = b0 + b1 * C1 + b2 * C2;   // Re(num)
                const v2f ni = b1 * S1 + b2 * S2;        // -Im(num)
                const v2f dr = a0 + a1 * C1 + a2 * C2;   // Re(den)
                const v2f di = a1 * S1 + a2 * S2;        // -Im(den)
                const v2f mn = nr * nr + ni * ni;
                const v2f md = dr * dr + di * di;
                v2f imn, imd;
                imn[0] = rcpf(mn[0]); imn[1] = rcpf(mn[1]);
                imd[0] = rcpf(md[0]); imd[1] = rcpf(md[1]);
                qp *= mn * imd;                           // |h|^2 running product
                Ur[j] = nr * imn; Ui[j] = ni * imn;
                Vr[j] = dr * imd; Vi[j] = di * imd;
            }
            const float q = qp[0] * qp[1];
            // mag = 10*log10(q); diff*(2/512)*(20/ln10)
            const float mag = 3.0102999566398120f * __log2f(q);
            const float K = (mag - tgt[k]) * 0.0339292563986915f;
            const v2f Kp = {K, K};
            const v2f Kn = {-K, -K};
            #pragma unroll
            for (int j = 0; j < 8; ++j) {
                const v2f KUr = Kp * Ur[j], KUi = Kp * Ui[j];
                const v2f KVr = Kn * Vr[j], KVi = Kn * Vi[j];
                if (k == 0) {
                    accv[0][j] = KUr;
                    accv[1][j] = C1 * KUr + S1 * KUi;
                    accv[2][j] = C2 * KUr + S2 * KUi;
                    accv[3][j] = KVr;
                    accv[4][j] = C1 * KVr + S1 * KVi;
                    accv[5][j] = C2 * KVr + S2 * KVi;
                } else {
                    accv[0][j] += KUr;
                    accv[1][j] += C1 * KUr + S1 * KUi;
                    accv[2][j] += C2 * KUr + S2 * KUi;
                    accv[3][j] += KVr;
                    accv[4][j] += C1 * KVr + S1 * KVi;
                    accv[5][j] += C2 * KVr + S2 * KVi;
                }
            }
        }

        // flatten to g = 6s+c order (pure register renaming, no instructions)
        float acc[96];
        #pragma unroll
        for (int c = 0; c < 6; ++c) {
            #pragma unroll
            for (int j = 0; j < 8; ++j) {
                acc[12 * j + c]     = accv[c][j][0];
                acc[12 * j + 6 + c] = accv[c][j][1];
            }
        }

        // ---- butterfly reduce-scatter: 128 cols (96 + zero pad) -> 2/lane ----
        float r64[64];
        #pragma unroll
        for (int i = 0; i < 64; ++i) {         // level 0: lane-mask 16
            float x = acc[i];
            float y = 0.0f;
            if (i + 64 < 96) y = acc[i + 64];
            swap16(x, y);
            r64[i] = x + y;
        }
        float r32[32];
        #pragma unroll
        for (int i = 0; i < 32; ++i) {         // level 1: lane-mask 32
            float x = r64[i], y = r64[i + 32];
            swap32(x, y);
            r32[i] = x + y;
        }
        float r16[16];
        #pragma unroll
        for (int i = 0; i < 16; ++i) {         // level 2: lane-mask 1 (DPP)
            const float x = r32[i], y = r32[i + 16];
            const float P  = up1 ? y : x;
            const float P2 = up1 ? x : y;
            r16[i] = P + dpp_mov<0xB1>(P2);
        }
        float r8[8];
        #pragma unroll
        for (int i = 0; i < 8; ++i) {          // level 3: lane-mask 2 (DPP)
            const float x = r16[i], y = r16[i + 8];
            const float P  = up2 ? y : x;
            const float P2 = up2 ? x : y;
            r8[i] = P + dpp_mov<0x4E>(P2);
        }
        float r4[4];
        #pragma unroll
        for (int i = 0; i < 4; ++i) {          // level 4: lane-mask 8 (DPP ror8)
            const float x = r8[i], y = r8[i + 4];
            const float P  = up8 ? y : x;
            const float P2 = up8 ? x : y;
            r4[i] = P + dpp_mov<0x128>(P2);
        }
        float r2[2];
        #pragma unroll
        for (int i = 0; i < 2; ++i) {          // level 5: lane-mask 4 (swizzle)
            const float x = r4[i], y = r4[i + 2];
            const float send = up4 ? x : y;
            const float recv = __shfl_xor(send, 4);
            r2[i] = (up4 ? y : x) + recv;
        }

        wgrad[wv][base]     = r2[0];
        wgrad[wv][base + 1] = r2[1];
        __syncthreads();

        if (t < 96) {   // t = c*16 + s in transposed layout
            const int c = t >> 4, s = t & 15;
            const int g = 6 * s + c;
            const float gsum = wgrad[0][g] + wgrad[1][g] + wgrad[2][g] + wgrad[3][g];
            sosT[t] = fmaf(-LRATE, gsum, sosT[t]);
        }
        __syncthreads();
    }

    if (t < 96) out[(t & 15) * 6 + (t >> 4)] = sosT[t];
}

extern "C" void kernel_launch(void* const* d_in, const int* in_sizes, int n_in,
                              void* d_out, int out_size, void* d_ws, size_t ws_size,
                              hipStream_t stream) {
    const float* target   = (const float*)d_in[0];   // (512,)
    const float* sos_init = (const float*)d_in[1];   // (1,16,6) = 96
    float* out = (float*)d_out;                      // 96 floats
    hipLaunchKernelGGL(sgd_filter_design_kernel, dim3(1), dim3(256), 0, stream,
                       target, sos_init, out);
}

// Round 4
// 2011.621 us; speedup vs baseline: 4.9267x; 1.1351x over previous
//
#include <hip/hip_runtime.h>
#include <math.h>

#define NITER 1000
#define LRATE 0.1f

typedef float v2f __attribute__((ext_vector_type(2)));
typedef unsigned int v2u __attribute__((ext_vector_type(2)));

__device__ __forceinline__ float rcpf(float x) { return __builtin_amdgcn_rcpf(x); }

template<int CTRL>
__device__ __forceinline__ float dpp_mov(float v) {
    return __int_as_float(__builtin_amdgcn_update_dpp(0, __float_as_int(v), CTRL, 0xF, 0xF, true));
}

__device__ __forceinline__ int lane_id() {
    return __builtin_amdgcn_mbcnt_hi(~0u, __builtin_amdgcn_mbcnt_lo(~0u, 0u));
}

__device__ __forceinline__ void swap16(float& x, float& y) {
#if __has_builtin(__builtin_amdgcn_permlane16_swap)
    v2u r = __builtin_amdgcn_permlane16_swap(__float_as_uint(x), __float_as_uint(y), false, false);
    x = __uint_as_float(r[0]);
    y = __uint_as_float(r[1]);
#else
    const bool up = lane_id() & 16;
    const float send = up ? x : y;
    const float recv = __shfl_xor(send, 16);
    x = up ? recv : x;
    y = up ? y : recv;
#endif
}

__device__ __forceinline__ void swap32(float& x, float& y) {
#if __has_builtin(__builtin_amdgcn_permlane32_swap)
    v2u r = __builtin_amdgcn_permlane32_swap(__float_as_uint(x), __float_as_uint(y), false, false);
    x = __uint_as_float(r[0]);
    y = __uint_as_float(r[1]);
#else
    const bool up = lane_id() & 32;
    const float send = up ? x : y;
    const float recv = __shfl_xor(send, 32);
    x = up ? recv : x;
    y = up ? y : recv;
#endif
}

// One block, 256 threads (4 waves = 1/SIMD). Wave w owns sections 4w..4w+3.
// Lane L (in every wave) owns frequencies 8L..8L+7 as 4 packed pairs.
__global__ __launch_bounds__(256, 1)
void sgd_filter_design_kernel(const float* __restrict__ target,
                              const float* __restrict__ sos_init,
                              float* __restrict__ out)
{
    const int t = threadIdx.x;
    const int w = t >> 6;
    const int L = t & 63;

    __shared__ __align__(16) float sosW[96];      // [w][s'][c] -> 24w + 6s' + c
    __shared__ __align__(16) float wq[4][512];    // per-wave partial |H|^2

    if (t < 96) {
        const int s = t / 6, c = t - 6 * s;
        sosW[24 * (s >> 2) + 6 * (s & 3) + c] = sos_init[t];
    }

    // Per-lane frequency constants, freqs n = 8L + 2i + h
    const float PI = 3.14159265358979323846f;
    v2f C1p[4], S1p[4], C2p[4], S2p[4], KT[4];
    #pragma unroll
    for (int i = 0; i < 4; ++i) {
        #pragma unroll
        for (int h = 0; h < 2; ++h) {
            const int n = 8 * L + 2 * i + h;
            const float wr = PI * (float)n / 511.0f;
            const float cc = cosf(wr), ss = sinf(wr);
            C1p[i][h] = cc;
            S1p[i][h] = ss;
            C2p[i][h] = 2.0f * cc * cc - 1.0f;
            S2p[i][h] = 2.0f * ss * cc;
            // K = KLOG*log2(q) - ALPHA*tgt; ALPHA = (2/512)*(20/ln10)
            KT[i][h] = 0.03392925639869154f * target[n];
        }
    }

    // Butterfly column owned by this lane; level masks [16,32,1,2,8,4],
    // column-bit weights [16,8,4,2,1,0].
    const int col = (L & 16) | ((L & 32) >> 2) | ((L & 1) << 2) | (L & 2) | ((L & 8) >> 3);
    const bool up1 = L & 1, up2 = L & 2, up8 = L & 8;

    __syncthreads();

    float val_own = 0.0f;
    if (col < 24) val_own = sosW[24 * w + col];

    for (int it = 0; it < NITER; ++it) {
        // this wave's 24 coefs (uniform-address broadcast loads)
        float cs[24];
        #pragma unroll
        for (int r = 0; r < 6; ++r) {
            const float4 v = *reinterpret_cast<const float4*>(&sosW[24 * w + 4 * r]);
            cs[4*r+0] = v.x; cs[4*r+1] = v.y; cs[4*r+2] = v.z; cs[4*r+3] = v.w;
        }

        // ---- forward over 4 sections x 4 freq-pairs ----
        v2f Ur[4][4], Ui[4][4], Vr[4][4], Vi[4][4];
        v2f qp[4] = {{1.f,1.f},{1.f,1.f},{1.f,1.f},{1.f,1.f}};
        #pragma unroll
        for (int sp = 0; sp < 4; ++sp) {
            const float b0 = cs[6*sp+0], b1 = cs[6*sp+1], b2 = cs[6*sp+2];
            const float a0 = cs[6*sp+3], a1 = cs[6*sp+4], a2 = cs[6*sp+5];
            #pragma unroll
            for (int i = 0; i < 4; ++i) {
                const v2f nr = b0 + b1 * C1p[i] + b2 * C2p[i];
                const v2f ni = b1 * S1p[i] + b2 * S2p[i];     // = -Im(num)
                const v2f dr = a0 + a1 * C1p[i] + a2 * C2p[i];
                const v2f di = a1 * S1p[i] + a2 * S2p[i];     // = -Im(den)
                const v2f mn = nr * nr + ni * ni;
                const v2f md = dr * dr + di * di;
                v2f imn, imd;
                imn[0] = rcpf(mn[0]); imn[1] = rcpf(mn[1]);
                imd[0] = rcpf(md[0]); imd[1] = rcpf(md[1]);
                qp[i] *= mn * imd;
                Ur[sp][i] = nr * imn; Ui[sp][i] = ni * imn;
                Vr[sp][i] = dr * imd; Vi[sp][i] = di * imd;
            }
        }

        // publish this wave's partial |H|^2 (8 contiguous freqs per lane)
        float4 q0, q1;
        q0.x = qp[0][0]; q0.y = qp[0][1]; q0.z = qp[1][0]; q0.w = qp[1][1];
        q1.x = qp[2][0]; q1.y = qp[2][1]; q1.z = qp[3][0]; q1.w = qp[3][1];
        *reinterpret_cast<float4*>(&wq[w][8 * L])     = q0;
        *reinterpret_cast<float4*>(&wq[w][8 * L + 4]) = q1;
        __syncthreads();

        // combine 4 wave-partials -> total |H|^2 per freq
        v2f qt[4];
        #pragma unroll
        for (int ww = 0; ww < 4; ++ww) {
            const float4 r0 = *reinterpret_cast<const float4*>(&wq[ww][8 * L]);
            const float4 r1 = *reinterpret_cast<const float4*>(&wq[ww][8 * L + 4]);
            if (ww == 0) {
                qt[0] = (v2f){r0.x, r0.y}; qt[1] = (v2f){r0.z, r0.w};
                qt[2] = (v2f){r1.x, r1.y}; qt[3] = (v2f){r1.z, r1.w};
            } else {
                qt[0] *= (v2f){r0.x, r0.y}; qt[1] *= (v2f){r0.z, r0.w};
                qt[2] *= (v2f){r1.x, r1.y}; qt[3] *= (v2f){r1.z, r1.w};
            }
        }

        // K per freq: K = KLOG*log2(q) - ALPHA*tgt
        v2f Kp[4];
        #pragma unroll
        for (int i = 0; i < 4; ++i) {
            v2f lg;
            lg[0] = __log2f(qt[i][0]);
            lg[1] = __log2f(qt[i][1]);
            Kp[i] = 0.10213724040f * lg - KT[i];
        }

        // ---- gradient accumulate (24 coefs, packed over freq pair) ----
        v2f acc[4][6];
        #pragma unroll
        for (int sp = 0; sp < 4; ++sp) {
            #pragma unroll
            for (int i = 0; i < 4; ++i) {
                const v2f KUr = Kp[i] * Ur[sp][i], KUi = Kp[i] * Ui[sp][i];
                const v2f KVr = Kp[i] * Vr[sp][i], KVi = Kp[i] * Vi[sp][i];
                if (i == 0) {
                    acc[sp][0] = KUr;
                    acc[sp][1] = C1p[i] * KUr + S1p[i] * KUi;
                    acc[sp][2] = C2p[i] * KUr + S2p[i] * KUi;
                    acc[sp][3] = -KVr;
                    acc[sp][4] = -C1p[i] * KVr - S1p[i] * KVi;
                    acc[sp][5] = -C2p[i] * KVr - S2p[i] * KVi;
                } else {
                    acc[sp][0] += KUr;
                    acc[sp][1] += C1p[i] * KUr + S1p[i] * KUi;
                    acc[sp][2] += C2p[i] * KUr + S2p[i] * KUi;
                    acc[sp][3] -= KVr;
                    acc[sp][4] = acc[sp][4] - C1p[i] * KVr - S1p[i] * KVi;
                    acc[sp][5] = acc[sp][5] - C2p[i] * KVr - S2p[i] * KVi;
                }
            }
        }

        // horizontal add of the freq-pair halves -> 24 scalars
        float g24[24];
        #pragma unroll
        for (int sp = 0; sp < 4; ++sp)
            #pragma unroll
            for (int c = 0; c < 6; ++c)
                g24[6 * sp + c] = acc[sp][c][0] + acc[sp][c][1];

        // ---- reduce-scatter over 64 lanes: 32 cols (24 real + 8 pad) ----
        float r16_[16];
        #pragma unroll
        for (int i = 0; i < 16; ++i) {            // mask 16
            float x = g24[i];
            float y = (i + 16 < 24) ? g24[i + 16] : 0.0f;
            swap16(x, y);
            r16_[i] = x + y;
        }
        float r8_[8];
        #pragma unroll
        for (int i = 0; i < 8; ++i) {             // mask 32
            float x = r16_[i], y = r16_[i + 8];
            swap32(x, y);
            r8_[i] = x + y;
        }
        float r4_[4];
        #pragma unroll
        for (int i = 0; i < 4; ++i) {             // mask 1 (DPP)
            const float x = r8_[i], y = r8_[i + 4];
            const float P = up1 ? y : x, Q = up1 ? x : y;
            r4_[i] = P + dpp_mov<0xB1>(Q);
        }
        float r2_[2];
        #pragma unroll
        for (int i = 0; i < 2; ++i) {             // mask 2 (DPP)
            const float x = r4_[i], y = r4_[i + 2];
            const float P = up2 ? y : x, Q = up2 ? x : y;
            r2_[i] = P + dpp_mov<0x4E>(Q);
        }
        float r1_;
        {                                          // mask 8 (DPP row_ror:8)
            const float x = r2_[0], y = r2_[1];
            const float P = up8 ? y : x, Q = up8 ? x : y;
            r1_ = P + dpp_mov<0x128>(Q);
        }
        const float tot = r1_ + __shfl_xor(r1_, 4);   // mask 4: full exchange

        // owner lanes (2 per col, identical values) update + publish
        if (col < 24) {
            val_own = fmaf(-LRATE, tot, val_own);
            sosW[24 * w + col] = val_own;
        }
        __syncthreads();
    }

    if (t < 96) {
        const int s = t / 6, c = t - 6 * s;
        out[t] = sosW[24 * (s >> 2) + 6 * (s & 3) + c];
    }
}

extern "C" void kernel_launch(void* const* d_in, const int* in_sizes, int n_in,
                              void* d_out, int out_size, void* d_ws, size_t ws_size,
                              hipStream_t stream) {
    const float* target   = (const float*)d_in[0];   // (512,)
    const float* sos_init = (const float*)d_in[1];   // (1,16,6) = 96
    float* out = (float*)d_out;                      // 96 floats
    hipLaunchKernelGGL(sgd_filter_design_kernel, dim3(1), dim3(256), 0, stream,
                       target, sos_init, out);
}